// Round 14
// baseline (3329.666 us; speedup 1.0000x reference)
//
#include <hip/hip_runtime.h>

typedef __attribute__((ext_vector_type(8))) short short8;
typedef __attribute__((ext_vector_type(4))) float f32x4;

#define DEV static __device__ __forceinline__

DEV unsigned short f2b(float f) {
    union { float f; unsigned u; } v; v.f = f;
    unsigned r = (v.u + 0x7FFFu + ((v.u >> 16) & 1u)) >> 16;
    return (unsigned short)r;
}
DEV float b2f(unsigned short s) {
    union { unsigned u; float f; } v; v.u = ((unsigned)s) << 16;
    return v.f;
}
DEV float sigm(float x) { return 1.0f / (1.0f + __expf(-x)); }

// ---------------- converts ----------------

__global__ void k_f2b(const float* __restrict__ src, unsigned short* __restrict__ dst, int n4) {
    int i = blockIdx.x * blockDim.x + threadIdx.x;
    if (i < n4) {
        float4 v = ((const float4*)src)[i];
        ushort4 o;
        o.x = f2b(v.x); o.y = f2b(v.y); o.z = f2b(v.z); o.w = f2b(v.w);
        ((ushort4*)dst)[i] = o;
    }
}

// dst[(4j+g)][k] = bf16(src[(g*1024+j)][k]); Kq = K/4
__global__ void k_perm(const float* __restrict__ src, unsigned short* __restrict__ dst, int Kq) {
    int i = blockIdx.x * blockDim.x + threadIdx.x;
    int total = 4096 * Kq;
    if (i >= total) return;
    int rp = i / Kq, kq = i - rp * Kq;
    int j = rp >> 2, g = rp & 3;
    float4 v = ((const float4*)src)[(size_t)(g * 1024 + j) * Kq + kq];
    ushort4 o;
    o.x = f2b(v.x); o.y = f2b(v.y); o.z = f2b(v.z); o.w = f2b(v.w);
    ((ushort4*)dst)[(size_t)rp * Kq + kq] = o;
}

__global__ void k_bias(const float* __restrict__ bi0, const float* __restrict__ bh0,
                       const float* __restrict__ bi1, const float* __restrict__ bh1,
                       float* __restrict__ d0, float* __restrict__ d1) {
    int i = blockIdx.x * blockDim.x + threadIdx.x;
    if (i < 4096) {
        int j = i >> 2, g = i & 3, s = g * 1024 + j;
        d0[i] = bi0[s] + bh0[s];
        d1[i] = bi1[s] + bh1[s];
    }
}

// writes initial h (packed 2xbf16) into parity-1 buffers; c as fp32
__global__ void k_init(const float* __restrict__ hx, const float* __restrict__ cx,
                       unsigned* __restrict__ hB0, unsigned* __restrict__ hB1,
                       float* __restrict__ c0, float* __restrict__ c1) {
    int i = blockIdx.x * blockDim.x + threadIdx.x;
    if (i < 128 * 512) {
        int b = i >> 9, j = i & 511;
        const float* p0 = hx + (size_t)b * 1024 + j * 2;
        const float* p1 = hx + 131072 + (size_t)b * 1024 + j * 2;
        hB0[i] = (unsigned)f2b(p0[0]) | ((unsigned)f2b(p0[1]) << 16);
        hB1[i] = (unsigned)f2b(p1[0]) | ((unsigned)f2b(p1[1]) << 16);
        c0[i * 2] = cx[i * 2];
        c0[i * 2 + 1] = cx[i * 2 + 1];
        c1[i * 2] = cx[131072 + i * 2];
        c1[i * 2 + 1] = cx[131072 + i * 2 + 1];
    }
}

// ---------------- xg GEMM: out[v][n] = sum_k A[row(v)][k] * W[n][k] ----------------
// m97-style staging: global_load_lds width=16 into LINEAR [128][32]bf16 tiles with a
// 16B-granule XOR swizzle (rule 21: linear dest + inverse-swizzled SOURCE + swizzled
// READ). Per wave, 2 issues/tile: issue j covers LDS bytes (w+j*4)*1024 + lane*16
// -> row = (w+j*4)*16 + (l>>2), granule qq = l&3; source granule = qq ^ (row&3).
__global__ __launch_bounds__(256) void k_gemm(
    const unsigned short* __restrict__ A, const unsigned short* __restrict__ W,
    unsigned short* __restrict__ out, int K, int t0, int TC) {
    __shared__ char ldsA[128 * 64];
    __shared__ char ldsB[128 * 64];
    const int tid = threadIdx.x;
    const int w = tid >> 6, l = tid & 63;
    const int wm = w >> 1, wn = w & 1;
    const int bm = blockIdx.x, bn = blockIdx.y;
    const int lr = l & 15, lkq = l >> 4;

    // staging rows/granules for this thread's two issues
    const int row0 = w * 16 + (l >> 2);
    const int row1 = (w + 4) * 16 + (l >> 2);
    const int qq = l & 3;
    const int inb0 = ((qq ^ (row0 & 3)) << 4);
    const int inb1 = ((qq ^ (row1 & 3)) << 4);
    const int v0 = bm * 128 + row0, v1 = bm * 128 + row1;
    const size_t ar0 = (size_t)((v0 / TC) * 256 + t0 + (v0 % TC));
    const size_t ar1 = (size_t)((v1 / TC) * 256 + t0 + (v1 % TC));
    const char* baseA0 = (const char*)A + ar0 * K * 2 + inb0;
    const char* baseA1 = (const char*)A + ar1 * K * 2 + inb1;
    const char* baseB0 = (const char*)W + (size_t)(bn * 128 + row0) * K * 2 + inb0;
    const char* baseB1 = (const char*)W + (size_t)(bn * 128 + row1) * K * 2 + inb1;

    f32x4 acc[4][4];
#pragma unroll
    for (int a = 0; a < 4; a++)
#pragma unroll
        for (int b = 0; b < 4; b++) acc[a][b] = (f32x4){0.f, 0.f, 0.f, 0.f};

    for (int ks = 0; ks < K; ks += 32) {
        __builtin_amdgcn_global_load_lds(
            (const __attribute__((address_space(1))) unsigned*)(baseA0 + (size_t)ks * 2),
            (__attribute__((address_space(3))) unsigned*)(ldsA + w * 1024), 16, 0, 0);
        __builtin_amdgcn_global_load_lds(
            (const __attribute__((address_space(1))) unsigned*)(baseA1 + (size_t)ks * 2),
            (__attribute__((address_space(3))) unsigned*)(ldsA + (w + 4) * 1024), 16, 0, 0);
        __builtin_amdgcn_global_load_lds(
            (const __attribute__((address_space(1))) unsigned*)(baseB0 + (size_t)ks * 2),
            (__attribute__((address_space(3))) unsigned*)(ldsB + w * 1024), 16, 0, 0);
        __builtin_amdgcn_global_load_lds(
            (const __attribute__((address_space(1))) unsigned*)(baseB1 + (size_t)ks * 2),
            (__attribute__((address_space(3))) unsigned*)(ldsB + (w + 4) * 1024), 16, 0, 0);
        __syncthreads();   // drains vmcnt (incl. global_load_lds) per compiler barrier semantics
        short8 af[4], bf[4];
#pragma unroll
        for (int mt = 0; mt < 4; mt++) {
            int row = wm * 64 + mt * 16 + lr;
            af[mt] = *(const short8*)(ldsA + row * 64 + ((lkq ^ (row & 3)) << 4));
        }
#pragma unroll
        for (int nt = 0; nt < 4; nt++) {
            int row = wn * 64 + nt * 16 + lr;
            bf[nt] = *(const short8*)(ldsB + row * 64 + ((lkq ^ (row & 3)) << 4));
        }
#pragma unroll
        for (int mt = 0; mt < 4; mt++)
#pragma unroll
            for (int nt = 0; nt < 4; nt++)
                acc[mt][nt] = __builtin_amdgcn_mfma_f32_16x16x32_bf16(af[mt], bf[nt], acc[mt][nt], 0, 0, 0);
        __syncthreads();
    }

#pragma unroll
    for (int mt = 0; mt < 4; mt++)
#pragma unroll
        for (int nt = 0; nt < 4; nt++)
#pragma unroll
            for (int v4 = 0; v4 < 4; v4++) {
                int vr = bm * 128 + wm * 64 + mt * 16 + (l >> 4) * 4 + v4;
                int col = bn * 128 + wn * 64 + nt * 16 + lr;
                out[(size_t)vr * 4096 + col] = f2b(acc[mt][nt][v4]);
            }
}

// ---------------- persistent recurrent kernel (r10 + XCD-local groups) ----------------
// 256 wgs (1/CU), 512 threads (8 waves). 8 groups x 32 wgs. NEW: group = blockIdx&7,
// nb = blockIdx>>3 — with round-robin dispatch, each group's 32 wgs land on ONE XCD,
// making the h/flag exchange XCD-local. Protocol is placement-agnostic (correct either
// way). Everything else byte-identical to r10 (PASS, 3046us):
// wg = (g: 16 batch rows) x (nb: 128 gate cols); waves 8-way split-K (128 k each);
// W cols 0..63 LDS (pitch 2064B), 64..127 regs (wreg[16]); per-iteration
// immediately-consumed atomic loads (r6-r8 batching quarantine); 3-stage reduce;
// per-wg flags 64B apart, absolute tag t+1, lane-parallel poll + __all.
template<int LAYER>
__global__ __launch_bounds__(512, 2) void k_lstm(
    const unsigned short* __restrict__ Wh,     // [4096][1024] bf16 gate-interleaved
    const unsigned short* __restrict__ xg,     // chunk: + b*(TC*4096) + dt*4096
    const float* __restrict__ bias,            // [4096]
    float* __restrict__ cbuf,                  // [128*1024] fp32
    unsigned* __restrict__ hA,                 // parity-0 h (packed 2xbf16) [128][512]
    unsigned* __restrict__ hB,                 // parity-1 h
    unsigned short* __restrict__ y0,           // layer0: h history [B][T][H] bf16 (null for L1)
    float* __restrict__ out,                   // layer1 only
    unsigned* __restrict__ flags,              // 8 groups x 32 wgs, stride 16 u32 (64B)
    int t0, int TC)
{
    extern __shared__ char smem[];
    char* ldsW = smem;                              // 64 rows x 2064 B
    float* P0 = (float*)(smem + 64 * 2064);         // [16][132]
    float* P1 = P0 + 16 * 132;
    float* P2 = P1 + 16 * 132;

    const int tid = threadIdx.x;
    const int g  = (int)blockIdx.x & 7;    // XCD-local group (round-robin dispatch)
    const int nb = (int)blockIdx.x >> 3;   // 0..31: gate cols nb*128..+128
    const int wv = tid >> 6;               // wave 0..7 = K eighth
    const int l  = tid & 63;
    const int lr = l & 15, lq = l >> 4;

    // stage LDS W: cols nb*128..+64, 64 rows x 2048B at pitch 2064B
    {
        const char* src = (const char*)(Wh + (size_t)nb * 128 * 1024);
#pragma unroll
        for (int it = 0; it < 16; it++) {
            int idx = it * 512 + tid;
            int row = idx >> 7, inr = (idx & 127) << 4;
            *(uint4*)(ldsW + row * 2064 + inr) = *(const uint4*)(src + (size_t)row * 2048 + inr);
        }
    }
    // reg W: cols nb*128+64..+128, this wave's K-eighth. 16 x short8 = 64 VGPR.
    short8 wreg[16];
    {
        const unsigned short* src = Wh + (size_t)(nb * 128 + 64) * 1024 + wv * 128;
#pragma unroll
        for (int ct = 0; ct < 4; ct++)
#pragma unroll
            for (int kk = 0; kk < 4; kk++)
                wreg[ct * 4 + kk] =
                    *(const short8*)(src + (size_t)(ct * 16 + lr) * 1024 + kk * 32 + lq * 8);
    }

    // epilogue fixed mapping (waves 0-3 only): thread -> (row er, 8 gates = 2 units)
    const int er = tid >> 4, ep = tid & 15;   // valid for tid < 256
    const int eb = g * 16 + (er & 15);
    const int ec0 = nb * 128 + ep * 8;
    const int eu0 = nb * 32 + ep * 2;
    float2 c2 = make_float2(0.f, 0.f);
    float4 bsA = make_float4(0.f, 0.f, 0.f, 0.f);
    float4 bsB = make_float4(0.f, 0.f, 0.f, 0.f);
    if (tid < 256) {
        c2 = *(const float2*)(cbuf + (size_t)eb * 1024 + eu0);
        bsA = *(const float4*)(bias + ec0);
        bsB = *(const float4*)(bias + ec0 + 4);
    }

    // mfma A addressing: row g*16+lr, k = wv*128 + kk*32 + lq*8 (u64 units)
    const size_t abase = (size_t)(g * 16 + lr) * 256 + (size_t)wv * 32 + lq * 2;
    const char* wp = ldsW + (size_t)lr * 2064 + wv * 256 + lq * 16;

    const unsigned* fp = flags + (size_t)(g * 32 + (l & 31)) * 16;
    unsigned* fmine = flags + (size_t)(g * 32 + nb) * 16;

    __syncthreads();

    for (int dt = 0; dt < TC; dt++) {
        const int t = t0 + dt;
        // prefetch xg (independent of h) — latency overlaps the poll
        uint4 xv = make_uint4(0, 0, 0, 0);
        if (tid < 256)
            xv = *(const uint4*)(xg + (size_t)eb * ((size_t)TC * 4096) + (size_t)dt * 4096 + ec0);

        if (t > 0) {
            const unsigned tgt = (unsigned)t;
            while (!__all(__hip_atomic_load(fp, __ATOMIC_RELAXED,
                                            __HIP_MEMORY_SCOPE_AGENT) >= tgt)) {}
        }

        const unsigned long long* ap =
            (const unsigned long long*)((t & 1) ? hA : hB) + abase;
        f32x4 acc[8];
#pragma unroll
        for (int i = 0; i < 8; i++) acc[i] = (f32x4){0.f, 0.f, 0.f, 0.f};
#pragma unroll
        for (int kk = 0; kk < 4; kk++) {
            union { unsigned long long u[2]; short8 s; } av;
            av.u[0] = __hip_atomic_load(ap + kk * 8,     __ATOMIC_RELAXED, __HIP_MEMORY_SCOPE_AGENT);
            av.u[1] = __hip_atomic_load(ap + kk * 8 + 1, __ATOMIC_RELAXED, __HIP_MEMORY_SCOPE_AGENT);
#pragma unroll
            for (int ct = 0; ct < 4; ct++) {
                short8 b = *(const short8*)(wp + (size_t)ct * 16 * 2064 + kk * 64);
                acc[ct] = __builtin_amdgcn_mfma_f32_16x16x32_bf16(av.s, b, acc[ct], 0, 0, 0);
            }
#pragma unroll
            for (int ct = 0; ct < 4; ct++)
                acc[4 + ct] = __builtin_amdgcn_mfma_f32_16x16x32_bf16(av.s, wreg[ct * 4 + kk], acc[4 + ct], 0, 0, 0);
        }

        // 3-stage split-K reduce of 8 partials into P0+P1+P2
        if (wv >= 5) {
            float* P = (wv == 5) ? P0 : (wv == 6) ? P1 : P2;
#pragma unroll
            for (int i = 0; i < 8; i++)
#pragma unroll
                for (int v = 0; v < 4; v++)
                    P[(lq * 4 + v) * 132 + i * 16 + lr] = acc[i][v];
        }
        __syncthreads();
        if (wv >= 2 && wv <= 4) {
            float* P = (wv == 2) ? P0 : (wv == 3) ? P1 : P2;
#pragma unroll
            for (int i = 0; i < 8; i++)
#pragma unroll
                for (int v = 0; v < 4; v++)
                    P[(lq * 4 + v) * 132 + i * 16 + lr] += acc[i][v];
        }
        __syncthreads();
        if (wv < 2) {
            float* P = (wv == 0) ? P0 : P1;
#pragma unroll
            for (int i = 0; i < 8; i++)
#pragma unroll
                for (int v = 0; v < 4; v++)
                    P[(lq * 4 + v) * 132 + i * 16 + lr] += acc[i][v];
        }
        __syncthreads();

        // epilogue (waves 0-3): sum 3 partials + xg + bias; cell update; h store
        float h0v = 0.f, h1v = 0.f;
        if (tid < 256) {
            const float* pa = P0 + er * 132 + ep * 8;
            const float* pb = P1 + er * 132 + ep * 8;
            const float* pc = P2 + er * 132 + ep * 8;
            const unsigned short* xs = (const unsigned short*)&xv;
            float p0 = pa[0] + pb[0] + pc[0] + b2f(xs[0]) + bsA.x;
            float p1 = pa[1] + pb[1] + pc[1] + b2f(xs[1]) + bsA.y;
            float p2 = pa[2] + pb[2] + pc[2] + b2f(xs[2]) + bsA.z;
            float p3 = pa[3] + pb[3] + pc[3] + b2f(xs[3]) + bsA.w;
            float q0 = pa[4] + pb[4] + pc[4] + b2f(xs[4]) + bsB.x;
            float q1 = pa[5] + pb[5] + pc[5] + b2f(xs[5]) + bsB.y;
            float q2 = pa[6] + pb[6] + pc[6] + b2f(xs[6]) + bsB.z;
            float q3 = pa[7] + pb[7] + pc[7] + b2f(xs[7]) + bsB.w;
            float i0 = sigm(p0), f0 = sigm(p1), gv0 = tanhf(p2), o0 = sigm(p3);
            float i1 = sigm(q0), f1 = sigm(q1), gv1 = tanhf(q2), o1 = sigm(q3);
            c2.x = f0 * c2.x + i0 * gv0;
            c2.y = f1 * c2.y + i1 * gv1;
            h0v = o0 * tanhf(c2.x);
            h1v = o1 * tanhf(c2.y);
            unsigned hp = (unsigned)f2b(h0v) | ((unsigned)f2b(h1v) << 16);
            unsigned* hout = (t & 1) ? hB : hA;
            __hip_atomic_store(hout + (size_t)eb * 512 + eu0 / 2, hp,
                               __ATOMIC_RELAXED, __HIP_MEMORY_SCOPE_AGENT);
        }
        __syncthreads();   // drains waves 0-3's h stores before signal
        if (tid == 0)
            __hip_atomic_store(fmine, (unsigned)(t + 1),
                               __ATOMIC_RELAXED, __HIP_MEMORY_SCOPE_AGENT);

        // off-critical-path stores AFTER signal
        if (tid < 256) {
            if (LAYER == 0) {
                unsigned hp = (unsigned)f2b(h0v) | ((unsigned)f2b(h1v) << 16);
                ((unsigned*)y0)[((size_t)eb * 256 + t) * 512 + eu0 / 2] = hp;
            } else {
                *(float2*)(out + ((size_t)eb * 256 + t) * 1024 + eu0) = make_float2(h0v, h1v);
                if (t == 255) {
                    *(float2*)(out + (size_t)128 * 256 * 1024 + (size_t)eb * 1024 + eu0) =
                        make_float2(h0v, h1v);
                    *(float2*)(out + (size_t)128 * 256 * 1024 + (size_t)128 * 1024 + (size_t)eb * 1024 + eu0) =
                        make_float2(c2.x, c2.y);
                }
            }
        }
    }
    // persist c for next chunk launch
    if (tid < 256)
        *(float2*)(cbuf + (size_t)eb * 1024 + eu0) = c2;
}

// ---------------- host ----------------

extern "C" void kernel_launch(void* const* d_in, const int* in_sizes, int n_in,
                              void* d_out, int out_size, void* d_ws, size_t ws_size,
                              hipStream_t stream) {
    const float* x    = (const float*)d_in[0];
    const float* hx0  = (const float*)d_in[1];
    const float* cx0  = (const float*)d_in[2];
    const float* Wih0 = (const float*)d_in[3];
    const float* Whh0 = (const float*)d_in[4];
    const float* bih0 = (const float*)d_in[5];
    const float* bhh0 = (const float*)d_in[6];
    const float* Wih1 = (const float*)d_in[7];
    const float* Whh1 = (const float*)d_in[8];
    const float* bih1 = (const float*)d_in[9];
    const float* bhh1 = (const float*)d_in[10];
    float* out = (float*)d_out;

    const int B = 128, T = 256, I = 256, H = 1024, G4 = 4096;
    const unsigned SMEM_BYTES = 64 * 2064 + 3 * 16 * 132 * 4;  // 157440
    const int FLAGS_U32 = 8 * 32 * 16;  // per layer

    hipFuncSetAttribute((const void*)&k_lstm<0>, hipFuncAttributeMaxDynamicSharedMemorySize, SMEM_BYTES);
    hipFuncSetAttribute((const void*)&k_lstm<1>, hipFuncAttributeMaxDynamicSharedMemorySize, SMEM_BYTES);

    char* p = (char*)d_ws;
    auto alloc = [&](size_t bytes) { char* r = p; p += (bytes + 255) & ~(size_t)255; return r; };
    unsigned short* xbf   = (unsigned short*)alloc((size_t)B * T * I * 2);
    unsigned short* Wih0p = (unsigned short*)alloc((size_t)G4 * I * 2);
    unsigned short* Whh0p = (unsigned short*)alloc((size_t)G4 * H * 2);
    unsigned short* Wih1p = (unsigned short*)alloc((size_t)G4 * H * 2);
    unsigned short* Whh1p = (unsigned short*)alloc((size_t)G4 * H * 2);
    float* bias0 = (float*)alloc(G4 * 4);
    float* bias1 = (float*)alloc(G4 * 4);
    unsigned short* y0 = (unsigned short*)alloc((size_t)B * T * H * 2);
    unsigned* hA0 = (unsigned*)alloc((size_t)B * 512 * 4);
    unsigned* hB0 = (unsigned*)alloc((size_t)B * 512 * 4);
    unsigned* hA1 = (unsigned*)alloc((size_t)B * 512 * 4);
    unsigned* hB1 = (unsigned*)alloc((size_t)B * 512 * 4);
    float* c0 = (float*)alloc((size_t)B * H * 4);
    float* c1 = (float*)alloc((size_t)B * H * 4);
    unsigned* flags0 = (unsigned*)alloc((size_t)2 * FLAGS_U32 * 4);
    unsigned* flags1 = flags0 + FLAGS_U32;
    size_t fixed = (size_t)(p - (char*)d_ws);
    int TC = 256;
    while (TC > 1 && fixed + (size_t)B * TC * G4 * 2 + 256 > ws_size) TC >>= 1;
    unsigned short* xg = (unsigned short*)alloc((size_t)B * TC * G4 * 2);

    // converts + flag reset (flags carry absolute t+1, monotone within a launch)
    hipMemsetAsync(flags0, 0, (size_t)2 * FLAGS_U32 * 4, stream);
    k_f2b<<<(B * T * I / 4 + 255) / 256, 256, 0, stream>>>(x, xbf, B * T * I / 4);
    k_perm<<<(G4 * (I / 4) + 255) / 256, 256, 0, stream>>>(Wih0, Wih0p, I / 4);
    k_perm<<<(G4 * (H / 4) + 255) / 256, 256, 0, stream>>>(Whh0, Whh0p, H / 4);
    k_perm<<<(G4 * (H / 4) + 255) / 256, 256, 0, stream>>>(Wih1, Wih1p, H / 4);
    k_perm<<<(G4 * (H / 4) + 255) / 256, 256, 0, stream>>>(Whh1, Whh1p, H / 4);
    k_bias<<<16, 256, 0, stream>>>(bih0, bhh0, bih1, bhh1, bias0, bias1);
    k_init<<<256, 256, 0, stream>>>(hx0, cx0, hB0, hB1, c0, c1);

    // ---- layer 0 ----
    for (int t0 = 0; t0 < T; t0 += TC) {
        k_gemm<<<dim3(TC, 32), 256, 0, stream>>>(xbf, Wih0p, xg, I, t0, TC);
        int t0v = t0, TCv = TC;
        const unsigned short* Whp = Whh0p;
        const unsigned short* xgp = xg;
        const float* bp = bias0;
        float* cp = c0;
        unsigned* ha = hA0; unsigned* hb = hB0;
        unsigned short* y0p = y0;
        float* op = nullptr;
        unsigned* fl = flags0;
        void* args[] = {&Whp, &xgp, &bp, &cp, &ha, &hb, &y0p, &op, &fl, &t0v, &TCv};
        hipLaunchCooperativeKernel((const void*)&k_lstm<0>, dim3(256), dim3(512), args, SMEM_BYTES, stream);
    }
    // ---- layer 1 ----
    for (int t0 = 0; t0 < T; t0 += TC) {
        k_gemm<<<dim3(TC, 32), 256, 0, stream>>>(y0, Wih1p, xg, H, t0, TC);
        int t0v = t0, TCv = TC;
        const unsigned short* Whp = Whh1p;
        const unsigned short* xgp = xg;
        const float* bp = bias1;
        float* cp = c1;
        unsigned* ha = hA1; unsigned* hb = hB1;
        unsigned short* y0p = nullptr;
        float* op = out;
        unsigned* fl = flags1;
        void* args[] = {&Whp, &xgp, &bp, &cp, &ha, &hb, &y0p, &op, &fl, &t0v, &TCv};
        hipLaunchCooperativeKernel((const void*)&k_lstm<1>, dim3(256), dim3(512), args, SMEM_BYTES, stream);
    }
}

// Round 15
// 3039.014 us; speedup vs baseline: 1.0956x; 1.0956x over previous
//
#include <hip/hip_runtime.h>

typedef __attribute__((ext_vector_type(8))) short short8;
typedef __attribute__((ext_vector_type(4))) float f32x4;

#define DEV static __device__ __forceinline__

DEV unsigned short f2b(float f) {
    union { float f; unsigned u; } v; v.f = f;
    unsigned r = (v.u + 0x7FFFu + ((v.u >> 16) & 1u)) >> 16;
    return (unsigned short)r;
}
DEV float b2f(unsigned short s) {
    union { unsigned u; float f; } v; v.u = ((unsigned)s) << 16;
    return v.f;
}
DEV float sigm(float x) { return 1.0f / (1.0f + __expf(-x)); }

// ---------------- converts ----------------

__global__ void k_f2b(const float* __restrict__ src, unsigned short* __restrict__ dst, int n4) {
    int i = blockIdx.x * blockDim.x + threadIdx.x;
    if (i < n4) {
        float4 v = ((const float4*)src)[i];
        ushort4 o;
        o.x = f2b(v.x); o.y = f2b(v.y); o.z = f2b(v.z); o.w = f2b(v.w);
        ((ushort4*)dst)[i] = o;
    }
}

// dst[(4j+g)][k] = bf16(src[(g*1024+j)][k]); Kq = K/4
__global__ void k_perm(const float* __restrict__ src, unsigned short* __restrict__ dst, int Kq) {
    int i = blockIdx.x * blockDim.x + threadIdx.x;
    int total = 4096 * Kq;
    if (i >= total) return;
    int rp = i / Kq, kq = i - rp * Kq;
    int j = rp >> 2, g = rp & 3;
    float4 v = ((const float4*)src)[(size_t)(g * 1024 + j) * Kq + kq];
    ushort4 o;
    o.x = f2b(v.x); o.y = f2b(v.y); o.z = f2b(v.z); o.w = f2b(v.w);
    ((ushort4*)dst)[(size_t)rp * Kq + kq] = o;
}

__global__ void k_bias(const float* __restrict__ bi0, const float* __restrict__ bh0,
                       const float* __restrict__ bi1, const float* __restrict__ bh1,
                       float* __restrict__ d0, float* __restrict__ d1) {
    int i = blockIdx.x * blockDim.x + threadIdx.x;
    if (i < 4096) {
        int j = i >> 2, g = i & 3, s = g * 1024 + j;
        d0[i] = bi0[s] + bh0[s];
        d1[i] = bi1[s] + bh1[s];
    }
}

// writes initial h (packed 2xbf16) into parity-1 buffers; c as fp32
__global__ void k_init(const float* __restrict__ hx, const float* __restrict__ cx,
                       unsigned* __restrict__ hB0, unsigned* __restrict__ hB1,
                       float* __restrict__ c0, float* __restrict__ c1) {
    int i = blockIdx.x * blockDim.x + threadIdx.x;
    if (i < 128 * 512) {
        int b = i >> 9, j = i & 511;
        const float* p0 = hx + (size_t)b * 1024 + j * 2;
        const float* p1 = hx + 131072 + (size_t)b * 1024 + j * 2;
        hB0[i] = (unsigned)f2b(p0[0]) | ((unsigned)f2b(p0[1]) << 16);
        hB1[i] = (unsigned)f2b(p1[0]) | ((unsigned)f2b(p1[1]) << 16);
        c0[i * 2] = cx[i * 2];
        c0[i * 2 + 1] = cx[i * 2 + 1];
        c1[i * 2] = cx[131072 + i * 2];
        c1[i * 2 + 1] = cx[131072 + i * 2 + 1];
    }
}

// ---------------- xg GEMM: out[v][n] = sum_k A[row(v)][k] * W[n][k] ----------------
__global__ __launch_bounds__(256) void k_gemm(
    const unsigned short* __restrict__ A, const unsigned short* __restrict__ W,
    unsigned short* __restrict__ out, int K, int t0, int TC) {
    __shared__ unsigned short ldsA[128 * 40];
    __shared__ unsigned short ldsB[128 * 40];
    const int tid = threadIdx.x;
    const int w = tid >> 6, l = tid & 63;
    const int wm = w >> 1, wn = w & 1;
    const int bm = blockIdx.x, bn = blockIdx.y;
    const int lr = l & 15, lk = (l >> 4) * 8;

    const int row0 = tid >> 2, inb = (tid & 3) << 4;
    const int row1 = row0 + 64;
    const int v0 = bm * 128 + row0, v1 = bm * 128 + row1;
    const size_t ar0 = (size_t)((v0 / TC) * 256 + t0 + (v0 % TC));
    const size_t ar1 = (size_t)((v1 / TC) * 256 + t0 + (v1 % TC));
    const size_t br0 = (size_t)(bn * 128 + row0);
    const size_t br1 = (size_t)(bn * 128 + row1);

    f32x4 acc[4][4];
#pragma unroll
    for (int a = 0; a < 4; a++)
#pragma unroll
        for (int b = 0; b < 4; b++) acc[a][b] = (f32x4){0.f, 0.f, 0.f, 0.f};

    for (int ks = 0; ks < K; ks += 32) {
        uint4 a0 = *(const uint4*)((const char*)A + (ar0 * K + ks) * 2 + inb);
        uint4 a1 = *(const uint4*)((const char*)A + (ar1 * K + ks) * 2 + inb);
        uint4 b0 = *(const uint4*)((const char*)W + (br0 * K + ks) * 2 + inb);
        uint4 b1 = *(const uint4*)((const char*)W + (br1 * K + ks) * 2 + inb);
        *(uint4*)((char*)ldsA + row0 * 80 + inb) = a0;
        *(uint4*)((char*)ldsA + row1 * 80 + inb) = a1;
        *(uint4*)((char*)ldsB + row0 * 80 + inb) = b0;
        *(uint4*)((char*)ldsB + row1 * 80 + inb) = b1;
        __syncthreads();
        short8 af[4], bf[4];
#pragma unroll
        for (int mt = 0; mt < 4; mt++)
            af[mt] = *(const short8*)((const char*)ldsA + (wm * 64 + mt * 16 + lr) * 80 + lk * 2);
#pragma unroll
        for (int nt = 0; nt < 4; nt++)
            bf[nt] = *(const short8*)((const char*)ldsB + (wn * 64 + nt * 16 + lr) * 80 + lk * 2);
#pragma unroll
        for (int mt = 0; mt < 4; mt++)
#pragma unroll
            for (int nt = 0; nt < 4; nt++)
                acc[mt][nt] = __builtin_amdgcn_mfma_f32_16x16x32_bf16(af[mt], bf[nt], acc[mt][nt], 0, 0, 0);
        __syncthreads();
    }

#pragma unroll
    for (int mt = 0; mt < 4; mt++)
#pragma unroll
        for (int nt = 0; nt < 4; nt++)
#pragma unroll
            for (int v4 = 0; v4 < 4; v4++) {
                int vr = bm * 128 + wm * 64 + mt * 16 + (l >> 4) * 4 + v4;
                int col = bn * 128 + wn * 64 + nt * 16 + lr;
                out[(size_t)vr * 4096 + col] = f2b(acc[mt][nt][v4]);
            }
}

// ---------------- persistent recurrent kernel (r10, best-known) ----------------
// 256 wgs (1/CU), 512 threads (8 waves, 2/SIMD). 8 groups x 32 wgs.
// wg = (g: 16 batch rows) x (nb: 128 gate cols). Waves: 8-way split-K (128 k each).
// W cols 0..63 in LDS (pitch 2064B), cols 64..127 in regs (short8 wreg[16] = 64 VGPR).
// SIGNALING: per-producer flags (64B stride, absolute tag t+1). Wave w's k-slice
// (units w*128..+128) is produced by exactly wgs nb=w*4..w*4+3 -> each wave
// lane-parallel-polls its 4 flags (lane l loads flag[w*4+(l&3)]; one load = one RTT)
// and starts its load+MFMA independently. Depth-2 ping-pong safety: wg stores h(t+1)
// only after all its 8 waves saw flags>=t+1 from all 32 group wgs; each wg's flag(t)
// follows its completed h(t-1) reads. Load/MFMA inner loop: per-iteration
// immediately-consumed atomic loads (r6-r8 batching quarantine — do NOT batch).
template<int LAYER>
__global__ __launch_bounds__(512, 2) void k_lstm(
    const unsigned short* __restrict__ Wh,     // [4096][1024] bf16 gate-interleaved
    const unsigned short* __restrict__ xg,     // chunk: + b*(TC*4096) + dt*4096
    const float* __restrict__ bias,            // [4096]
    float* __restrict__ cbuf,                  // [128*1024] fp32
    unsigned* __restrict__ hA,                 // parity-0 h (packed 2xbf16) [128][512]
    unsigned* __restrict__ hB,                 // parity-1 h
    unsigned short* __restrict__ y0,           // layer0: h history [B][T][H] bf16 (null for L1)
    float* __restrict__ out,                   // layer1 only
    unsigned* __restrict__ flags,              // 8 groups x 32 wgs, stride 16 u32 (64B)
    int t0, int TC)
{
    extern __shared__ char smem[];
    char* ldsW = smem;                              // 64 rows x 2064 B
    float* P0 = (float*)(smem + 64 * 2064);         // [16][132]
    float* P1 = P0 + 16 * 132;
    float* P2 = P1 + 16 * 132;

    const int tid = threadIdx.x;
    const int g  = (int)blockIdx.x >> 5;   // 0..7: batch rows g*16..+16
    const int nb = (int)blockIdx.x & 31;   // 0..31: gate cols nb*128..+128
    const int wv = tid >> 6;               // wave 0..7 = K eighth
    const int l  = tid & 63;
    const int lr = l & 15, lq = l >> 4;

    // stage LDS W: cols nb*128..+64, 64 rows x 2048B at pitch 2064B
    {
        const char* src = (const char*)(Wh + (size_t)nb * 128 * 1024);
#pragma unroll
        for (int it = 0; it < 16; it++) {
            int idx = it * 512 + tid;
            int row = idx >> 7, inr = (idx & 127) << 4;
            *(uint4*)(ldsW + row * 2064 + inr) = *(const uint4*)(src + (size_t)row * 2048 + inr);
        }
    }
    // reg W: cols nb*128+64..+128, this wave's K-eighth. 16 x short8 = 64 VGPR.
    short8 wreg[16];
    {
        const unsigned short* src = Wh + (size_t)(nb * 128 + 64) * 1024 + wv * 128;
#pragma unroll
        for (int ct = 0; ct < 4; ct++)
#pragma unroll
            for (int kk = 0; kk < 4; kk++)
                wreg[ct * 4 + kk] =
                    *(const short8*)(src + (size_t)(ct * 16 + lr) * 1024 + kk * 32 + lq * 8);
    }

    // epilogue fixed mapping (waves 0-3 only): thread -> (row er, 8 gates = 2 units)
    const int er = tid >> 4, ep = tid & 15;   // valid for tid < 256
    const int eb = g * 16 + (er & 15);
    const int ec0 = nb * 128 + ep * 8;
    const int eu0 = nb * 32 + ep * 2;
    float2 c2 = make_float2(0.f, 0.f);
    float4 bsA = make_float4(0.f, 0.f, 0.f, 0.f);
    float4 bsB = make_float4(0.f, 0.f, 0.f, 0.f);
    if (tid < 256) {
        c2 = *(const float2*)(cbuf + (size_t)eb * 1024 + eu0);
        bsA = *(const float4*)(bias + ec0);
        bsB = *(const float4*)(bias + ec0 + 4);
    }

    // mfma A addressing: row g*16+lr, k = wv*128 + kk*32 + lq*8 (u64 units)
    const size_t abase = (size_t)(g * 16 + lr) * 256 + (size_t)wv * 32 + lq * 2;
    // LDS B addressing: row lr (+ct*16), byte offset in row = wv*256 + lq*16 (+kk*64)
    const char* wp = ldsW + (size_t)lr * 2064 + wv * 256 + lq * 16;

    // my wave's 4 producers (lane-parallel poll), and my wg's flag
    const unsigned* fpw = flags + (size_t)(g * 32 + wv * 4 + (l & 3)) * 16;
    unsigned* fmine = flags + (size_t)(g * 32 + nb) * 16;

    __syncthreads();

    for (int dt = 0; dt < TC; dt++) {
        const int t = t0 + dt;
        // prefetch xg (independent of h) — latency overlaps the poll
        uint4 xv = make_uint4(0, 0, 0, 0);
        if (tid < 256)
            xv = *(const uint4*)(xg + (size_t)eb * ((size_t)TC * 4096) + (size_t)dt * 4096 + ec0);

        if (t > 0) {
            const unsigned tgt = (unsigned)t;
            while (!__all(__hip_atomic_load(fpw, __ATOMIC_RELAXED,
                                            __HIP_MEMORY_SCOPE_AGENT) >= tgt)) {}
        }

        const unsigned long long* ap =
            (const unsigned long long*)((t & 1) ? hA : hB) + abase;
        f32x4 acc[8];
#pragma unroll
        for (int i = 0; i < 8; i++) acc[i] = (f32x4){0.f, 0.f, 0.f, 0.f};
#pragma unroll
        for (int kk = 0; kk < 4; kk++) {
            union { unsigned long long u[2]; short8 s; } av;
            av.u[0] = __hip_atomic_load(ap + kk * 8,     __ATOMIC_RELAXED, __HIP_MEMORY_SCOPE_AGENT);
            av.u[1] = __hip_atomic_load(ap + kk * 8 + 1, __ATOMIC_RELAXED, __HIP_MEMORY_SCOPE_AGENT);
#pragma unroll
            for (int ct = 0; ct < 4; ct++) {
                short8 b = *(const short8*)(wp + (size_t)ct * 16 * 2064 + kk * 64);
                acc[ct] = __builtin_amdgcn_mfma_f32_16x16x32_bf16(av.s, b, acc[ct], 0, 0, 0);
            }
#pragma unroll
            for (int ct = 0; ct < 4; ct++)
                acc[4 + ct] = __builtin_amdgcn_mfma_f32_16x16x32_bf16(av.s, wreg[ct * 4 + kk], acc[4 + ct], 0, 0, 0);
        }

        // 3-stage split-K reduce of 8 partials into P0+P1+P2
        if (wv >= 5) {
            float* P = (wv == 5) ? P0 : (wv == 6) ? P1 : P2;
#pragma unroll
            for (int i = 0; i < 8; i++)
#pragma unroll
                for (int v = 0; v < 4; v++)
                    P[(lq * 4 + v) * 132 + i * 16 + lr] = acc[i][v];
        }
        __syncthreads();
        if (wv >= 2 && wv <= 4) {
            float* P = (wv == 2) ? P0 : (wv == 3) ? P1 : P2;
#pragma unroll
            for (int i = 0; i < 8; i++)
#pragma unroll
                for (int v = 0; v < 4; v++)
                    P[(lq * 4 + v) * 132 + i * 16 + lr] += acc[i][v];
        }
        __syncthreads();
        if (wv < 2) {
            float* P = (wv == 0) ? P0 : P1;
#pragma unroll
            for (int i = 0; i < 8; i++)
#pragma unroll
                for (int v = 0; v < 4; v++)
                    P[(lq * 4 + v) * 132 + i * 16 + lr] += acc[i][v];
        }
        __syncthreads();

        // epilogue (waves 0-3): sum 3 partials + xg + bias; cell update; h store
        float h0v = 0.f, h1v = 0.f;
        if (tid < 256) {
            const float* pa = P0 + er * 132 + ep * 8;
            const float* pb = P1 + er * 132 + ep * 8;
            const float* pc = P2 + er * 132 + ep * 8;
            const unsigned short* xs = (const unsigned short*)&xv;
            float p0 = pa[0] + pb[0] + pc[0] + b2f(xs[0]) + bsA.x;
            float p1 = pa[1] + pb[1] + pc[1] + b2f(xs[1]) + bsA.y;
            float p2 = pa[2] + pb[2] + pc[2] + b2f(xs[2]) + bsA.z;
            float p3 = pa[3] + pb[3] + pc[3] + b2f(xs[3]) + bsA.w;
            float q0 = pa[4] + pb[4] + pc[4] + b2f(xs[4]) + bsB.x;
            float q1 = pa[5] + pb[5] + pc[5] + b2f(xs[5]) + bsB.y;
            float q2 = pa[6] + pb[6] + pc[6] + b2f(xs[6]) + bsB.z;
            float q3 = pa[7] + pb[7] + pc[7] + b2f(xs[7]) + bsB.w;
            float i0 = sigm(p0), f0 = sigm(p1), gv0 = tanhf(p2), o0 = sigm(p3);
            float i1 = sigm(q0), f1 = sigm(q1), gv1 = tanhf(q2), o1 = sigm(q3);
            c2.x = f0 * c2.x + i0 * gv0;
            c2.y = f1 * c2.y + i1 * gv1;
            h0v = o0 * tanhf(c2.x);
            h1v = o1 * tanhf(c2.y);
            unsigned hp = (unsigned)f2b(h0v) | ((unsigned)f2b(h1v) << 16);
            unsigned* hout = (t & 1) ? hB : hA;
            __hip_atomic_store(hout + (size_t)eb * 512 + eu0 / 2, hp,
                               __ATOMIC_RELAXED, __HIP_MEMORY_SCOPE_AGENT);
        }
        __syncthreads();   // drains waves 0-3's h stores before signal
        if (tid == 0)
            __hip_atomic_store(fmine, (unsigned)(t + 1),
                               __ATOMIC_RELAXED, __HIP_MEMORY_SCOPE_AGENT);

        // off-critical-path stores AFTER signal
        if (tid < 256) {
            if (LAYER == 0) {
                unsigned hp = (unsigned)f2b(h0v) | ((unsigned)f2b(h1v) << 16);
                ((unsigned*)y0)[((size_t)eb * 256 + t) * 512 + eu0 / 2] = hp;
            } else {
                *(float2*)(out + ((size_t)eb * 256 + t) * 1024 + eu0) = make_float2(h0v, h1v);
                if (t == 255) {
                    *(float2*)(out + (size_t)128 * 256 * 1024 + (size_t)eb * 1024 + eu0) =
                        make_float2(h0v, h1v);
                    *(float2*)(out + (size_t)128 * 256 * 1024 + (size_t)128 * 1024 + (size_t)eb * 1024 + eu0) =
                        make_float2(c2.x, c2.y);
                }
            }
        }
    }
    // persist c for next chunk launch
    if (tid < 256)
        *(float2*)(cbuf + (size_t)eb * 1024 + eu0) = c2;
}

// ---------------- host ----------------

extern "C" void kernel_launch(void* const* d_in, const int* in_sizes, int n_in,
                              void* d_out, int out_size, void* d_ws, size_t ws_size,
                              hipStream_t stream) {
    const float* x    = (const float*)d_in[0];
    const float* hx0  = (const float*)d_in[1];
    const float* cx0  = (const float*)d_in[2];
    const float* Wih0 = (const float*)d_in[3];
    const float* Whh0 = (const float*)d_in[4];
    const float* bih0 = (const float*)d_in[5];
    const float* bhh0 = (const float*)d_in[6];
    const float* Wih1 = (const float*)d_in[7];
    const float* Whh1 = (const float*)d_in[8];
    const float* bih1 = (const float*)d_in[9];
    const float* bhh1 = (const float*)d_in[10];
    float* out = (float*)d_out;

    const int B = 128, T = 256, I = 256, H = 1024, G4 = 4096;
    const unsigned SMEM_BYTES = 64 * 2064 + 3 * 16 * 132 * 4;  // 157440
    const int FLAGS_U32 = 8 * 32 * 16;  // per layer

    hipFuncSetAttribute((const void*)&k_lstm<0>, hipFuncAttributeMaxDynamicSharedMemorySize, SMEM_BYTES);
    hipFuncSetAttribute((const void*)&k_lstm<1>, hipFuncAttributeMaxDynamicSharedMemorySize, SMEM_BYTES);

    char* p = (char*)d_ws;
    auto alloc = [&](size_t bytes) { char* r = p; p += (bytes + 255) & ~(size_t)255; return r; };
    unsigned short* xbf   = (unsigned short*)alloc((size_t)B * T * I * 2);
    unsigned short* Wih0p = (unsigned short*)alloc((size_t)G4 * I * 2);
    unsigned short* Whh0p = (unsigned short*)alloc((size_t)G4 * H * 2);
    unsigned short* Wih1p = (unsigned short*)alloc((size_t)G4 * H * 2);
    unsigned short* Whh1p = (unsigned short*)alloc((size_t)G4 * H * 2);
    float* bias0 = (float*)alloc(G4 * 4);
    float* bias1 = (float*)alloc(G4 * 4);
    unsigned short* y0 = (unsigned short*)alloc((size_t)B * T * H * 2);
    unsigned* hA0 = (unsigned*)alloc((size_t)B * 512 * 4);
    unsigned* hB0 = (unsigned*)alloc((size_t)B * 512 * 4);
    unsigned* hA1 = (unsigned*)alloc((size_t)B * 512 * 4);
    unsigned* hB1 = (unsigned*)alloc((size_t)B * 512 * 4);
    float* c0 = (float*)alloc((size_t)B * H * 4);
    float* c1 = (float*)alloc((size_t)B * H * 4);
    unsigned* flags0 = (unsigned*)alloc((size_t)2 * FLAGS_U32 * 4);
    unsigned* flags1 = flags0 + FLAGS_U32;
    size_t fixed = (size_t)(p - (char*)d_ws);
    int TC = 256;
    while (TC > 1 && fixed + (size_t)B * TC * G4 * 2 + 256 > ws_size) TC >>= 1;
    unsigned short* xg = (unsigned short*)alloc((size_t)B * TC * G4 * 2);

    // converts + flag reset (flags carry absolute t+1, monotone within a launch)
    hipMemsetAsync(flags0, 0, (size_t)2 * FLAGS_U32 * 4, stream);
    k_f2b<<<(B * T * I / 4 + 255) / 256, 256, 0, stream>>>(x, xbf, B * T * I / 4);
    k_perm<<<(G4 * (I / 4) + 255) / 256, 256, 0, stream>>>(Wih0, Wih0p, I / 4);
    k_perm<<<(G4 * (H / 4) + 255) / 256, 256, 0, stream>>>(Whh0, Whh0p, H / 4);
    k_perm<<<(G4 * (H / 4) + 255) / 256, 256, 0, stream>>>(Wih1, Wih1p, H / 4);
    k_perm<<<(G4 * (H / 4) + 255) / 256, 256, 0, stream>>>(Whh1, Whh1p, H / 4);
    k_bias<<<16, 256, 0, stream>>>(bih0, bhh0, bih1, bhh1, bias0, bias1);
    k_init<<<256, 256, 0, stream>>>(hx0, cx0, hB0, hB1, c0, c1);

    // ---- layer 0 ----
    for (int t0 = 0; t0 < T; t0 += TC) {
        k_gemm<<<dim3(TC, 32), 256, 0, stream>>>(xbf, Wih0p, xg, I, t0, TC);
        int t0v = t0, TCv = TC;
        const unsigned short* Whp = Whh0p;
        const unsigned short* xgp = xg;
        const float* bp = bias0;
        float* cp = c0;
        unsigned* ha = hA0; unsigned* hb = hB0;
        unsigned short* y0p = y0;
        float* op = nullptr;
        unsigned* fl = flags0;
        void* args[] = {&Whp, &xgp, &bp, &cp, &ha, &hb, &y0p, &op, &fl, &t0v, &TCv};
        hipLaunchCooperativeKernel((const void*)&k_lstm<0>, dim3(256), dim3(512), args, SMEM_BYTES, stream);
    }
    // ---- layer 1 ----
    for (int t0 = 0; t0 < T; t0 += TC) {
        k_gemm<<<dim3(TC, 32), 256, 0, stream>>>(y0, Wih1p, xg, H, t0, TC);
        int t0v = t0, TCv = TC;
        const unsigned short* Whp = Whh1p;
        const unsigned short* xgp = xg;
        const float* bp = bias1;
        float* cp = c1;
        unsigned* ha = hA1; unsigned* hb = hB1;
        unsigned short* y0p = nullptr;
        float* op = out;
        unsigned* fl = flags1;
        void* args[] = {&Whp, &xgp, &bp, &cp, &ha, &hb, &y0p, &op, &fl, &t0v, &TCv};
        hipLaunchCooperativeKernel((const void*)&k_lstm<1>, dim3(256), dim3(512), args, SMEM_BYTES, stream);
    }
}